// Round 5
// baseline (96.741 us; speedup 1.0000x reference)
//
#include <hip/hip_runtime.h>

#define IMG_H 224
#define IMG_W 224
#define PLANE (IMG_H * IMG_W)    // 50176
#define NBLK  (256 * 7)          // 1792 band-blocks: image x 32-row band
#define TPB   128

typedef float fl4 __attribute__((ext_vector_type(4)));

// ---- ordered-uint mapping for float min/max ----
__device__ __forceinline__ unsigned int ford(float f) {
    unsigned int u = __float_as_uint(f);
    return (u & 0x80000000u) ? ~u : (u | 0x80000000u);
}
__device__ __forceinline__ float funord(unsigned int u) {
    unsigned int v = (u & 0x80000000u) ? (u & 0x7FFFFFFFu) : ~u;
    return __uint_as_float(v);
}

// Exact two-stage Sobel vesselness for border-ring pixels.
__device__ __forceinline__ float ves_exact(const float xs[36][44], int lr, int lc,
                                           int gr, int gc)
{
    float acc = 0.f;
    #pragma unroll
    for (int dr = -1; dr <= 1; ++dr) {
        #pragma unroll
        for (int dc = -1; dc <= 1; ++dc) {
            const int qr = gr + dr, qc = gc + dc;
            if ((unsigned)qr < IMG_H && (unsigned)qc < IMG_W) {
                const int a = lr + dr, b = lc + dc;
                const float gx = (xs[a-1][b+1] - xs[a-1][b-1])
                               + 2.f * (xs[a][b+1] - xs[a][b-1])
                               + (xs[a+1][b+1] - xs[a+1][b-1]);
                const float gy = (xs[a+1][b-1] - xs[a-1][b-1])
                               + 2.f * (xs[a+1][b] - xs[a-1][b])
                               + (xs[a+1][b+1] - xs[a-1][b+1]);
                const float kxw = (float)dc * ((dr == 0) ? 2.f : 1.f);
                const float kyw = (float)dr * ((dc == 0) ? 2.f : 1.f);
                acc += kxw * gx + kyw * gy;
            }
        }
    }
    return fabsf(acc);
}

struct TV { float xv[2][4], rec[2][4], ves[2][4]; };

__device__ __forceinline__ void stage_tile(const float* __restrict__ xp,
                                           float xs[36][44], int r0, int c0, int tid)
{
    #pragma unroll
    for (int k = 0; k < 3; ++k) {           // 360 float4 slots, 128 threads
        const int i = tid + k * TPB;
        if (i < 360) {
            const int r = i / 10, c4 = i - 10 * r;
            const int gr = r0 - 2 + r, gc = c0 - 4 + 4 * c4;
            fl4 v = (fl4)0.f;
            if ((unsigned)gr < IMG_H && (unsigned)gc < IMG_W)
                v = *(const fl4*)(xp + gr * IMG_W + gc);
            *(fl4*)&xs[r][4 * c4] = v;
        }
    }
}

// thread (tx,ty) owns 2 rows x 4 cols of the 32x32 tile; interior ves via the
// composed separable 5x5; border ring via exact two-stage. (Validated in R3.)
__device__ __forceinline__ void compute_tile(const float xs[36][44], int tx, int ty,
                                             int r0, int c0, TV& tv)
{
    float uu[6][4], ww[6][4];
    #pragma unroll
    for (int rr = 0; rr < 6; ++rr) {
        float ck[8];
        #pragma unroll
        for (int k = 0; k < 8; ++k) ck[k] = xs[2*ty + rr][4*tx + 2 + k];
        #pragma unroll
        for (int j = 0; j < 4; ++j) {
            uu[rr][j] = ck[j] - 2.f * ck[j+2] + ck[j+4];
            ww[rr][j] = ck[j] + 4.f * ck[j+1] + 6.f * ck[j+2] + 4.f * ck[j+3] + ck[j+4];
        }
    }
    #pragma unroll
    for (int s = 0; s < 2; ++s)
        #pragma unroll
        for (int j = 0; j < 4; ++j)
            tv.xv[s][j] = xs[2*ty + 2 + s][4*tx + 4 + j];

    #pragma unroll
    for (int q = 0; q < 2; ++q) {
        const float a = tv.xv[0][2*q], b = tv.xv[0][2*q+1];
        const float c = tv.xv[1][2*q], d = tv.xv[1][2*q+1];
        const float h0 = (a + b + c + d) * 0.5f;
        const float h1 = (a - b + c - d) * 0.5f;
        const float h2 = (a + b - c - d) * 0.5f;
        const float h3 = (a - b - c + d) * 0.5f;
        const float s0 = 0.1f*h0, s1 = 2.5f*h1, s2 = 2.5f*h2, s3 = 3.5f*h3;
        tv.rec[0][2*q]   = (s0 + s1 + s2 + s3) * 0.5f;
        tv.rec[0][2*q+1] = (s0 - s1 + s2 - s3) * 0.5f;
        tv.rec[1][2*q]   = (s0 + s1 - s2 - s3) * 0.5f;
        tv.rec[1][2*q+1] = (s0 - s1 - s2 + s3) * 0.5f;
    }

    #pragma unroll
    for (int s = 0; s < 2; ++s) {
        const int gr = r0 + 2*ty + s;
        const bool er = (gr == 0) | (gr == IMG_H - 1);
        #pragma unroll
        for (int j = 0; j < 4; ++j) {
            float t = uu[s][j] + 4.f*uu[s+1][j] + 6.f*uu[s+2][j] + 4.f*uu[s+3][j] + uu[s+4][j]
                    + ww[s][j] - 2.f*ww[s+2][j] + ww[s+4][j];
            float vv = fabsf(t);
            const int gc = c0 + 4*tx + j;
            if (er | (gc == 0) | (gc == IMG_W - 1))
                vv = ves_exact(xs, 2*ty + 2 + s, 4*tx + 4 + j, gr, gc);
            tv.ves[s][j] = vv;
        }
    }
}

// Pass 1: block = one 32-row band (7 tiles) of one image -> one uint4 partial.
__global__ __launch_bounds__(TPB)
void pass1_kernel(const float* __restrict__ x, uint4* __restrict__ partials)
{
    __shared__ float xs[36][44];
    __shared__ unsigned int wred[2][4];

    const int bid = blockIdx.x;
    const int tx = threadIdx.x, ty = threadIdx.y;
    const int tid = ty * 8 + tx;
    const int img = bid / 7;
    const int r0  = (bid % 7) * 32;
    const float* xp = x + (size_t)img * 3 * PLANE;

    float rmn = 3.4e38f, rmx = -3.4e38f, vmn = 3.4e38f, vmx = -3.4e38f;
    for (int t = 0; t < 7; ++t) {
        const int c0 = t * 32;
        stage_tile(xp, xs, r0, c0, tid);
        __syncthreads();
        TV tv;
        compute_tile(xs, tx, ty, r0, c0, tv);
        #pragma unroll
        for (int s = 0; s < 2; ++s)
            #pragma unroll
            for (int j = 0; j < 4; ++j) {
                rmn = fminf(rmn, tv.rec[s][j]); rmx = fmaxf(rmx, tv.rec[s][j]);
                vmn = fminf(vmn, tv.ves[s][j]); vmx = fmaxf(vmx, tv.ves[s][j]);
            }
        __syncthreads();   // xs consumed before next stage overwrites
    }
    #pragma unroll
    for (int off = 32; off; off >>= 1) {
        rmn = fminf(rmn, __shfl_down(rmn, off));
        rmx = fmaxf(rmx, __shfl_down(rmx, off));
        vmn = fminf(vmn, __shfl_down(vmn, off));
        vmx = fmaxf(vmx, __shfl_down(vmx, off));
    }
    if ((tid & 63) == 0) {
        const int w = tid >> 6;
        wred[w][0] = ford(rmn); wred[w][1] = ford(rmx);
        wred[w][2] = ford(vmn); wred[w][3] = ford(vmx);
    }
    __syncthreads();
    if (tid == 0) {
        uint4 p;
        p.x = min(wred[0][0], wred[1][0]);
        p.y = max(wred[0][1], wred[1][1]);
        p.z = min(wred[0][2], wred[1][2]);
        p.w = max(wred[0][3], wred[1][3]);
        partials[bid] = p;
    }
}

// Reduce 1792 uint4 partials -> red[0..3]. One 1024-thread block, 28 KB read.
__global__ __launch_bounds__(1024)
void reduce_partials(const uint4* __restrict__ partials, unsigned int* __restrict__ red)
{
    __shared__ unsigned int wred[16][4];
    const int tid = threadIdx.x;
    unsigned int mn0 = 0xFFFFFFFFu, mx1 = 0u, mn2 = 0xFFFFFFFFu, mx3 = 0u;
    for (int i = tid; i < NBLK; i += 1024) {
        uint4 p = partials[i];
        mn0 = min(mn0, p.x); mx1 = max(mx1, p.y);
        mn2 = min(mn2, p.z); mx3 = max(mx3, p.w);
    }
    #pragma unroll
    for (int off = 32; off; off >>= 1) {
        mn0 = min(mn0, (unsigned)__shfl_down((int)mn0, off));
        mx1 = max(mx1, (unsigned)__shfl_down((int)mx1, off));
        mn2 = min(mn2, (unsigned)__shfl_down((int)mn2, off));
        mx3 = max(mx3, (unsigned)__shfl_down((int)mx3, off));
    }
    const int wave = tid >> 6;
    if ((tid & 63) == 0) {
        wred[wave][0] = mn0; wred[wave][1] = mx1;
        wred[wave][2] = mn2; wred[wave][3] = mx3;
    }
    __syncthreads();
    if (tid == 0) {
        unsigned int a0 = wred[0][0], a1 = wred[0][1], a2 = wred[0][2], a3 = wred[0][3];
        #pragma unroll
        for (int w = 1; w < 16; ++w) {
            a0 = min(a0, wred[w][0]); a1 = max(a1, wred[w][1]);
            a2 = min(a2, wred[w][2]); a3 = max(a3, wred[w][3]);
        }
        red[0] = a0; red[1] = a1; red[2] = a2; red[3] = a3;
    }
}

// Pass 2: same band decomposition; recompute (x L3-resident) + write 3 channels.
__global__ __launch_bounds__(TPB)
void pass2_kernel(const float* __restrict__ x, float* __restrict__ out,
                  const unsigned int* __restrict__ red)
{
    __shared__ float xs[36][44];

    const int bid = blockIdx.x;
    const int tx = threadIdx.x, ty = threadIdx.y;
    const int tid = ty * 8 + tx;
    const int img = bid / 7;
    const int r0  = (bid % 7) * 32;
    const float* xp = x + (size_t)img * 3 * PLANE;

    const float rmin = funord(red[0]), rmax = funord(red[1]);
    const float vmin = funord(red[2]), vmax = funord(red[3]);
    const float rsc = 1.f / (rmax - rmin + 1e-6f);
    const float vsc = 1.f / (vmax - vmin + 1e-6f);
    const float m0 = 0.485f, i0 = 1.f / 0.229f;
    const float m1 = 0.456f, i1 = 1.f / 0.224f;
    const float m2 = 0.406f, i2 = 1.f / 0.225f;

    for (int t = 0; t < 7; ++t) {
        const int c0 = t * 32;
        stage_tile(xp, xs, r0, c0, tid);
        __syncthreads();
        TV tv;
        compute_tile(xs, tx, ty, r0, c0, tv);

        float* op = out + (size_t)img * 3 * PLANE
                        + (size_t)(r0 + 2*ty) * IMG_W + (c0 + 4*tx);
        #pragma unroll
        for (int s = 0; s < 2; ++s) {
            fl4 o0, o1, o2;
            #pragma unroll
            for (int j = 0; j < 4; ++j) {
                o0[j] = (tv.xv[s][j] - m0) * i0;
                o1[j] = ((tv.rec[s][j] - rmin) * rsc - m1) * i1;
                o2[j] = ((tv.ves[s][j] - vmin) * vsc - m2) * i2;
            }
            __builtin_nontemporal_store(o0, (fl4*)(op + s * IMG_W));
            __builtin_nontemporal_store(o1, (fl4*)(op + s * IMG_W + PLANE));
            __builtin_nontemporal_store(o2, (fl4*)(op + s * IMG_W + 2 * PLANE));
        }
        __syncthreads();   // xs consumed before next stage overwrites
    }
}

extern "C" void kernel_launch(void* const* d_in, const int* in_sizes, int n_in,
                              void* d_out, int out_size, void* d_ws, size_t ws_size,
                              hipStream_t stream) {
    const float* x = (const float*)d_in[0];
    float* out = (float*)d_out;
    unsigned int* red = (unsigned int*)d_ws;           // 4 uints
    uint4* partials = (uint4*)((char*)d_ws + 16);      // NBLK uint4

    dim3 block(8, 16);
    pass1_kernel<<<dim3(NBLK), block, 0, stream>>>(x, partials);
    reduce_partials<<<1, 1024, 0, stream>>>(partials, red);
    pass2_kernel<<<dim3(NBLK), block, 0, stream>>>(x, out, red);
}

// Round 6
// 95.662 us; speedup vs baseline: 1.0113x; 1.0113x over previous
//
#include <hip/hip_runtime.h>
#include <hip/hip_fp16.h>

#define IMG_H 224
#define IMG_W 224
#define PLANE (IMG_H * IMG_W)    // 50176
#define NBLK  (256 * 7)          // 1792 band-blocks: image x 32-row band
#define TPB   128

typedef float fl4 __attribute__((ext_vector_type(4)));

// ws layout: [0,16) red | [16, 28688) partials | [32768, +25.7MB) rec fp16 | ves fp16
#define WS_PLANES_OFF 32768
#define WS_NEED (WS_PLANES_OFF + 2ull * 256 * PLANE * 2)

// ---- ordered-uint mapping for float min/max ----
__device__ __forceinline__ unsigned int ford(float f) {
    unsigned int u = __float_as_uint(f);
    return (u & 0x80000000u) ? ~u : (u | 0x80000000u);
}
__device__ __forceinline__ float funord(unsigned int u) {
    unsigned int v = (u & 0x80000000u) ? (u & 0x7FFFFFFFu) : ~u;
    return __uint_as_float(v);
}

// Exact two-stage Sobel vesselness for border-ring pixels.
__device__ __forceinline__ float ves_exact(const float xs[36][44], int lr, int lc,
                                           int gr, int gc)
{
    float acc = 0.f;
    #pragma unroll
    for (int dr = -1; dr <= 1; ++dr) {
        #pragma unroll
        for (int dc = -1; dc <= 1; ++dc) {
            const int qr = gr + dr, qc = gc + dc;
            if ((unsigned)qr < IMG_H && (unsigned)qc < IMG_W) {
                const int a = lr + dr, b = lc + dc;
                const float gx = (xs[a-1][b+1] - xs[a-1][b-1])
                               + 2.f * (xs[a][b+1] - xs[a][b-1])
                               + (xs[a+1][b+1] - xs[a+1][b-1]);
                const float gy = (xs[a+1][b-1] - xs[a-1][b-1])
                               + 2.f * (xs[a+1][b] - xs[a-1][b])
                               + (xs[a+1][b+1] - xs[a-1][b+1]);
                const float kxw = (float)dc * ((dr == 0) ? 2.f : 1.f);
                const float kyw = (float)dr * ((dc == 0) ? 2.f : 1.f);
                acc += kxw * gx + kyw * gy;
            }
        }
    }
    return fabsf(acc);
}

struct TV { float xv[2][4], rec[2][4], ves[2][4]; };

__device__ __forceinline__ void stage_tile(const float* __restrict__ xp,
                                           float xs[36][44], int r0, int c0, int tid)
{
    #pragma unroll
    for (int k = 0; k < 3; ++k) {           // 360 float4 slots, 128 threads
        const int i = tid + k * TPB;
        if (i < 360) {
            const int r = i / 10, c4 = i - 10 * r;
            const int gr = r0 - 2 + r, gc = c0 - 4 + 4 * c4;
            fl4 v = (fl4)0.f;
            if ((unsigned)gr < IMG_H && (unsigned)gc < IMG_W)
                v = *(const fl4*)(xp + gr * IMG_W + gc);
            *(fl4*)&xs[r][4 * c4] = v;
        }
    }
}

// thread (tx,ty) owns 2 rows x 4 cols of the 32x32 tile (validated in R3/R5).
__device__ __forceinline__ void compute_tile(const float xs[36][44], int tx, int ty,
                                             int r0, int c0, TV& tv)
{
    float uu[6][4], ww[6][4];
    #pragma unroll
    for (int rr = 0; rr < 6; ++rr) {
        float ck[8];
        #pragma unroll
        for (int k = 0; k < 8; ++k) ck[k] = xs[2*ty + rr][4*tx + 2 + k];
        #pragma unroll
        for (int j = 0; j < 4; ++j) {
            uu[rr][j] = ck[j] - 2.f * ck[j+2] + ck[j+4];
            ww[rr][j] = ck[j] + 4.f * ck[j+1] + 6.f * ck[j+2] + 4.f * ck[j+3] + ck[j+4];
        }
    }
    #pragma unroll
    for (int s = 0; s < 2; ++s)
        #pragma unroll
        for (int j = 0; j < 4; ++j)
            tv.xv[s][j] = xs[2*ty + 2 + s][4*tx + 4 + j];

    #pragma unroll
    for (int q = 0; q < 2; ++q) {
        const float a = tv.xv[0][2*q], b = tv.xv[0][2*q+1];
        const float c = tv.xv[1][2*q], d = tv.xv[1][2*q+1];
        const float h0 = (a + b + c + d) * 0.5f;
        const float h1 = (a - b + c - d) * 0.5f;
        const float h2 = (a + b - c - d) * 0.5f;
        const float h3 = (a - b - c + d) * 0.5f;
        const float s0 = 0.1f*h0, s1 = 2.5f*h1, s2 = 2.5f*h2, s3 = 3.5f*h3;
        tv.rec[0][2*q]   = (s0 + s1 + s2 + s3) * 0.5f;
        tv.rec[0][2*q+1] = (s0 - s1 + s2 - s3) * 0.5f;
        tv.rec[1][2*q]   = (s0 + s1 - s2 - s3) * 0.5f;
        tv.rec[1][2*q+1] = (s0 - s1 - s2 + s3) * 0.5f;
    }

    #pragma unroll
    for (int s = 0; s < 2; ++s) {
        const int gr = r0 + 2*ty + s;
        const bool er = (gr == 0) | (gr == IMG_H - 1);
        #pragma unroll
        for (int j = 0; j < 4; ++j) {
            float t = uu[s][j] + 4.f*uu[s+1][j] + 6.f*uu[s+2][j] + 4.f*uu[s+3][j] + uu[s+4][j]
                    + ww[s][j] - 2.f*ww[s+2][j] + ww[s+4][j];
            float vv = fabsf(t);
            const int gc = c0 + 4*tx + j;
            if (er | (gc == 0) | (gc == IMG_W - 1))
                vv = ves_exact(xs, 2*ty + 2 + s, 4*tx + 4 + j, gr, gc);
            tv.ves[s][j] = vv;
        }
    }
}

// Pass 1: block = one 32-row band (7 tiles). Always emits uint4 partial.
// STORE: also writes normalized ch0 to out and rec/ves fp16 planes to ws.
template<bool STORE>
__global__ __launch_bounds__(TPB)
void pass1_kernel(const float* __restrict__ x, float* __restrict__ out,
                  __half* __restrict__ recp, __half* __restrict__ vesp,
                  uint4* __restrict__ partials)
{
    __shared__ float xs[36][44];
    __shared__ unsigned int wred[2][4];

    const int bid = blockIdx.x;
    const int tx = threadIdx.x, ty = threadIdx.y;
    const int tid = ty * 8 + tx;
    const int img = bid / 7;
    const int r0  = (bid % 7) * 32;
    const float* xp = x + (size_t)img * 3 * PLANE;

    float rmn = 3.4e38f, rmx = -3.4e38f, vmn = 3.4e38f, vmx = -3.4e38f;
    for (int t = 0; t < 7; ++t) {
        const int c0 = t * 32;
        stage_tile(xp, xs, r0, c0, tid);
        __syncthreads();
        TV tv;
        compute_tile(xs, tx, ty, r0, c0, tv);
        #pragma unroll
        for (int s = 0; s < 2; ++s)
            #pragma unroll
            for (int j = 0; j < 4; ++j) {
                rmn = fminf(rmn, tv.rec[s][j]); rmx = fmaxf(rmx, tv.rec[s][j]);
                vmn = fminf(vmn, tv.ves[s][j]); vmx = fmaxf(vmx, tv.ves[s][j]);
            }
        if constexpr (STORE) {
            const float m0 = 0.485f, i0 = 1.f / 0.229f;
            float* op = out + (size_t)img * 3 * PLANE
                            + (size_t)(r0 + 2*ty) * IMG_W + (c0 + 4*tx);
            const size_t poff = (size_t)img * PLANE
                              + (size_t)(r0 + 2*ty) * IMG_W + (c0 + 4*tx);
            #pragma unroll
            for (int s = 0; s < 2; ++s) {
                fl4 o0;
                #pragma unroll
                for (int j = 0; j < 4; ++j) o0[j] = (tv.xv[s][j] - m0) * i0;
                __builtin_nontemporal_store(o0, (fl4*)(op + s * IMG_W));
                __half2* rp = (__half2*)(recp + poff + s * IMG_W);
                __half2* vp = (__half2*)(vesp + poff + s * IMG_W);
                rp[0] = __floats2half2_rn(tv.rec[s][0], tv.rec[s][1]);
                rp[1] = __floats2half2_rn(tv.rec[s][2], tv.rec[s][3]);
                vp[0] = __floats2half2_rn(tv.ves[s][0], tv.ves[s][1]);
                vp[1] = __floats2half2_rn(tv.ves[s][2], tv.ves[s][3]);
            }
        }
        __syncthreads();   // xs consumed before next stage overwrites
    }
    #pragma unroll
    for (int off = 32; off; off >>= 1) {
        rmn = fminf(rmn, __shfl_down(rmn, off));
        rmx = fmaxf(rmx, __shfl_down(rmx, off));
        vmn = fminf(vmn, __shfl_down(vmn, off));
        vmx = fmaxf(vmx, __shfl_down(vmx, off));
    }
    if ((tid & 63) == 0) {
        const int w = tid >> 6;
        wred[w][0] = ford(rmn); wred[w][1] = ford(rmx);
        wred[w][2] = ford(vmn); wred[w][3] = ford(vmx);
    }
    __syncthreads();
    if (tid == 0) {
        uint4 p;
        p.x = min(wred[0][0], wred[1][0]);
        p.y = max(wred[0][1], wred[1][1]);
        p.z = min(wred[0][2], wred[1][2]);
        p.w = max(wred[0][3], wred[1][3]);
        partials[bid] = p;
    }
}

// Reduce 1792 uint4 partials -> red[0..3].
__global__ __launch_bounds__(1024)
void reduce_partials(const uint4* __restrict__ partials, unsigned int* __restrict__ red)
{
    __shared__ unsigned int wred[16][4];
    const int tid = threadIdx.x;
    unsigned int mn0 = 0xFFFFFFFFu, mx1 = 0u, mn2 = 0xFFFFFFFFu, mx3 = 0u;
    for (int i = tid; i < NBLK; i += 1024) {
        uint4 p = partials[i];
        mn0 = min(mn0, p.x); mx1 = max(mx1, p.y);
        mn2 = min(mn2, p.z); mx3 = max(mx3, p.w);
    }
    #pragma unroll
    for (int off = 32; off; off >>= 1) {
        mn0 = min(mn0, (unsigned)__shfl_down((int)mn0, off));
        mx1 = max(mx1, (unsigned)__shfl_down((int)mx1, off));
        mn2 = min(mn2, (unsigned)__shfl_down((int)mn2, off));
        mx3 = max(mx3, (unsigned)__shfl_down((int)mx3, off));
    }
    const int wave = tid >> 6;
    if ((tid & 63) == 0) {
        wred[wave][0] = mn0; wred[wave][1] = mx1;
        wred[wave][2] = mn2; wred[wave][3] = mx3;
    }
    __syncthreads();
    if (tid == 0) {
        unsigned int a0 = wred[0][0], a1 = wred[0][1], a2 = wred[0][2], a3 = wred[0][3];
        #pragma unroll
        for (int w = 1; w < 16; ++w) {
            a0 = min(a0, wred[w][0]); a1 = max(a1, wred[w][1]);
            a2 = min(a2, wred[w][2]); a3 = max(a3, wred[w][3]);
        }
        red[0] = a0; red[1] = a1; red[2] = a2; red[3] = a3;
    }
}

// Fast pass 2: pure elementwise affine over the fp16 planes. grid(49, 256),
// 128 threads, 8 px/thread: 49*128*8 = 50176 = PLANE exactly.
__global__ __launch_bounds__(TPB)
void pass2_affine(const __half* __restrict__ recp, const __half* __restrict__ vesp,
                  float* __restrict__ out, const unsigned int* __restrict__ red)
{
    const int img = blockIdx.y;
    const int off = (blockIdx.x * TPB + threadIdx.x) * 8;

    const float rmin = funord(red[0]), rmax = funord(red[1]);
    const float vmin = funord(red[2]), vmax = funord(red[3]);
    const float rsc = 1.f / (rmax - rmin + 1e-6f);
    const float vsc = 1.f / (vmax - vmin + 1e-6f);
    const float m1 = 0.456f, i1 = 1.f / 0.224f;
    const float m2 = 0.406f, i2 = 1.f / 0.225f;

    const size_t pbase = (size_t)img * PLANE + off;
    const uint4 rv = *(const uint4*)(recp + pbase);
    const uint4 vv = *(const uint4*)(vesp + pbase);
    const __half2* hr = (const __half2*)&rv;
    const __half2* hv = (const __half2*)&vv;

    fl4 o1a, o1b, o2a, o2b;
    #pragma unroll
    for (int i = 0; i < 2; ++i) {
        float2 r = __half22float2(hr[i]);
        float2 v = __half22float2(hv[i]);
        o1a[2*i]   = ((r.x - rmin) * rsc - m1) * i1;
        o1a[2*i+1] = ((r.y - rmin) * rsc - m1) * i1;
        o2a[2*i]   = ((v.x - vmin) * vsc - m2) * i2;
        o2a[2*i+1] = ((v.y - vmin) * vsc - m2) * i2;
    }
    #pragma unroll
    for (int i = 0; i < 2; ++i) {
        float2 r = __half22float2(hr[2 + i]);
        float2 v = __half22float2(hv[2 + i]);
        o1b[2*i]   = ((r.x - rmin) * rsc - m1) * i1;
        o1b[2*i+1] = ((r.y - rmin) * rsc - m1) * i1;
        o2b[2*i]   = ((v.x - vmin) * vsc - m2) * i2;
        o2b[2*i+1] = ((v.y - vmin) * vsc - m2) * i2;
    }

    float* o1 = out + (size_t)img * 3 * PLANE + PLANE + off;
    float* o2 = o1 + PLANE;
    __builtin_nontemporal_store(o1a, (fl4*)o1);
    __builtin_nontemporal_store(o1b, (fl4*)(o1 + 4));
    __builtin_nontemporal_store(o2a, (fl4*)o2);
    __builtin_nontemporal_store(o2b, (fl4*)(o2 + 4));
}

// Fallback pass 2 (R5-validated): recompute + write all 3 channels.
__global__ __launch_bounds__(TPB)
void pass2_full(const float* __restrict__ x, float* __restrict__ out,
                const unsigned int* __restrict__ red)
{
    __shared__ float xs[36][44];

    const int bid = blockIdx.x;
    const int tx = threadIdx.x, ty = threadIdx.y;
    const int tid = ty * 8 + tx;
    const int img = bid / 7;
    const int r0  = (bid % 7) * 32;
    const float* xp = x + (size_t)img * 3 * PLANE;

    const float rmin = funord(red[0]), rmax = funord(red[1]);
    const float vmin = funord(red[2]), vmax = funord(red[3]);
    const float rsc = 1.f / (rmax - rmin + 1e-6f);
    const float vsc = 1.f / (vmax - vmin + 1e-6f);
    const float m0 = 0.485f, i0 = 1.f / 0.229f;
    const float m1 = 0.456f, i1 = 1.f / 0.224f;
    const float m2 = 0.406f, i2 = 1.f / 0.225f;

    for (int t = 0; t < 7; ++t) {
        const int c0 = t * 32;
        stage_tile(xp, xs, r0, c0, tid);
        __syncthreads();
        TV tv;
        compute_tile(xs, tx, ty, r0, c0, tv);

        float* op = out + (size_t)img * 3 * PLANE
                        + (size_t)(r0 + 2*ty) * IMG_W + (c0 + 4*tx);
        #pragma unroll
        for (int s = 0; s < 2; ++s) {
            fl4 o0, o1, o2;
            #pragma unroll
            for (int j = 0; j < 4; ++j) {
                o0[j] = (tv.xv[s][j] - m0) * i0;
                o1[j] = ((tv.rec[s][j] - rmin) * rsc - m1) * i1;
                o2[j] = ((tv.ves[s][j] - vmin) * vsc - m2) * i2;
            }
            __builtin_nontemporal_store(o0, (fl4*)(op + s * IMG_W));
            __builtin_nontemporal_store(o1, (fl4*)(op + s * IMG_W + PLANE));
            __builtin_nontemporal_store(o2, (fl4*)(op + s * IMG_W + 2 * PLANE));
        }
        __syncthreads();
    }
}

extern "C" void kernel_launch(void* const* d_in, const int* in_sizes, int n_in,
                              void* d_out, int out_size, void* d_ws, size_t ws_size,
                              hipStream_t stream) {
    const float* x = (const float*)d_in[0];
    float* out = (float*)d_out;
    unsigned int* red = (unsigned int*)d_ws;
    uint4* partials = (uint4*)((char*)d_ws + 16);
    __half* recp = (__half*)((char*)d_ws + WS_PLANES_OFF);
    __half* vesp = recp + (size_t)256 * PLANE;

    dim3 block(8, 16);
    if (ws_size >= WS_NEED) {
        pass1_kernel<true><<<dim3(NBLK), block, 0, stream>>>(x, out, recp, vesp, partials);
        reduce_partials<<<1, 1024, 0, stream>>>(partials, red);
        pass2_affine<<<dim3(49, 256), TPB, 0, stream>>>(recp, vesp, out, red);
    } else {
        pass1_kernel<false><<<dim3(NBLK), block, 0, stream>>>(x, out, recp, vesp, partials);
        reduce_partials<<<1, 1024, 0, stream>>>(partials, red);
        pass2_full<<<dim3(NBLK), block, 0, stream>>>(x, out, red);
    }
}